// Round 5
// baseline (404.506 us; speedup 1.0000x reference)
//
#include <hip/hip_runtime.h>
#include <stdint.h>

// VQ: inputs (16,64,64,64) f32 BCHW, codebook (1024,64) f32.
// out[0:65536] = argmin indices as float; out[65536:] = gathered rows, BCHW.
//
// r5: codebook lives in REGISTERS as pre-split bf16 hi/lo MFMA A-fragments
// (8 waves x 128 codes, loaded once per block, no LDS restage, no barriers
// in the main loop). z staged once to LDS (hi/lo, swizzled). 3-pass MFMA
// filter + packed-key (m1,m2) + exact rescreen (all r4-validated numerics).
#define NUM_K 1024
#define CDIM  64
#define NPOS  65536
#define NPB   256      // positions per block
#define DELTA 8e-5f
#define BIAS  0.25f    // keeps s = cnorm+BIAS-2dot positive (CS bound 0.18)

typedef __attribute__((ext_vector_type(8))) short short8;
typedef __attribute__((ext_vector_type(4))) float f32x4;

union U4S8 { uint4 u; short8 s; };

// ---- kernel 1: exact codebook squared norms (numpy pairwise, r2-validated) ----
__global__ __launch_bounds__(256) void vq_cnorm_kernel(
    const float* __restrict__ cb, float* __restrict__ cnorm) {
#pragma clang fp contract(off)
    int k = blockIdx.x * 256 + threadIdx.x;
    const float* row = cb + k * CDIM;
    float r[8];
#pragma unroll
    for (int j = 0; j < 8; ++j) r[j] = row[j] * row[j];
#pragma unroll
    for (int i = 1; i < 8; ++i) {
#pragma unroll
        for (int j = 0; j < 8; ++j) {
            float s = row[i * 8 + j] * row[i * 8 + j];
            r[j] = r[j] + s;
        }
    }
    cnorm[k] = ((r[0] + r[1]) + (r[2] + r[3])) + ((r[4] + r[5]) + (r[6] + r[7]));
}

__device__ __forceinline__ void cvt_pair(float f0, float f1,
                                         uint32_t& hp, uint32_t& lp) {
    uint32_t h;
    asm("v_cvt_pk_bf16_f32 %0, %1, %2" : "=v"(h) : "v"(f0), "v"(f1));
    float h0 = __uint_as_float(h << 16);
    float h1 = __uint_as_float(h & 0xFFFF0000u);
    float r0 = f0 - h0, r1 = f1 - h1;
    uint32_t l;
    asm("v_cvt_pk_bf16_f32 %0, %1, %2" : "=v"(l) : "v"(r0), "v"(r1));
    hp = h; lp = l;
}

__device__ __forceinline__ unsigned long long shflxor64(unsigned long long v, int off) {
    unsigned lo = (unsigned)v, hi = (unsigned)(v >> 32);
    lo = (unsigned)__shfl_xor((int)lo, off);
    hi = (unsigned)__shfl_xor((int)hi, off);
    return ((unsigned long long)hi << 32) | lo;
}

#define RFMA4(acc, zb, v)                          \
    acc = fmaf(zv[(zb) + 0], v.x, acc);            \
    acc = fmaf(zv[(zb) + 1], v.y, acc);            \
    acc = fmaf(zv[(zb) + 2], v.z, acc);            \
    acc = fmaf(zv[(zb) + 3], v.w, acc);

// LDS map (bytes)
#define OFF_SFIN  0        // 256 int
#define OFF_AMBC  1024
#define OFF_AMBL  1088     // 256 int
#define OFF_ZSC   2112     // 8 waves * 64 f32
#define OFF_ZHI   4224     // 256 pos * 128 B (bf16 hi, dim-contig, swizzled)
#define OFF_ZLO   36992
#define OFF_WRED  69760    // 256 pos * 9 slots * 8 B (pad 9 kills conflicts)
#define SMEM_SZ   88192

__global__ __launch_bounds__(512, 2) void vq_main_kernel(
    const float* __restrict__ in, const float* __restrict__ cb,
    const float* __restrict__ cnorm, float* __restrict__ out) {
#pragma clang fp contract(off)
    const int tid  = threadIdx.x;
    const int lane = tid & 63;
    const int wv   = tid >> 6;          // 0..7
    const int n0g  = blockIdx.x * NPB;
    const int b    = n0g >> 12;
    const int hw0  = n0g & 4095;

    __shared__ __align__(16) unsigned char smem[SMEM_SZ];
    int*    sfin    = (int*)(smem + OFF_SFIN);
    int*    ambcnt  = (int*)(smem + OFF_AMBC);
    int*    amblist = (int*)(smem + OFF_AMBL);
    float*  zsc     = (float*)(smem + OFF_ZSC);
    unsigned char* zhi_ = smem + OFF_ZHI;
    unsigned char* zlo_ = smem + OFF_ZLO;
    float2* wred    = (float2*)(smem + OFF_WRED);

    if (tid == 0) *ambcnt = 0;

    // ---- codebook A-fragments into registers (once; no LDS, no transpose) ----
    // wave wv owns codes Kw..Kw+127 (8 ktiles of 16). Fragment lane l of
    // (kt,ks): code Kw+kt*16+(l&15), dims 32*ks+8*(l>>4)..+7 (contiguous f32).
    const int Kw = wv << 7;
    short8 afh[8][2], afl[8][2];
    f32x4  cnv[8];
#pragma unroll
    for (int kt = 0; kt < 8; ++kt) {
        const int krow = Kw + kt * 16 + (lane & 15);
        const float4* rp = (const float4*)(cb + krow * CDIM);
#pragma unroll
        for (int ks = 0; ks < 2; ++ks) {
            const int o4 = (32 * ks + 8 * (lane >> 4)) >> 2;
            float4 v0 = rp[o4], v1 = rp[o4 + 1];
            float f[8] = {v0.x, v0.y, v0.z, v0.w, v1.x, v1.y, v1.z, v1.w};
            U4S8 H, L;
            uint32_t hp, lp;
            cvt_pair(f[0], f[1], hp, lp); H.u.x = hp; L.u.x = lp;
            cvt_pair(f[2], f[3], hp, lp); H.u.y = hp; L.u.y = lp;
            cvt_pair(f[4], f[5], hp, lp); H.u.z = hp; L.u.z = lp;
            cvt_pair(f[6], f[7], hp, lp); H.u.w = hp; L.u.w = lp;
            afh[kt][ks] = H.s; afl[kt][ks] = L.s;
        }
        f32x4 cn = *(const f32x4*)(cnorm + Kw + kt * 16 + ((lane >> 4) << 2));
#pragma unroll
        for (int r = 0; r < 4; ++r) cn[r] = cn[r] + BIAS;
        cnv[kt] = cn;
    }

    // ---- stage z: 256 pos, bf16 hi/lo, dim-contig rows, xor-swizzled ----
    {
        const int n   = tid & 255;
        const int chl = tid >> 8;       // 0/1 -> dims 0..31 / 32..63
        const float* zp = in + (((size_t)b * CDIM) << 12) + hw0 + n;
#pragma unroll
        for (int s = 0; s < 4; ++s) {
            float f[8];
#pragma unroll
            for (int j = 0; j < 8; ++j)
                f[j] = zp[(size_t)(chl * 32 + s * 8 + j) << 12];
            U4S8 H, L;
            uint32_t hp, lp;
            cvt_pair(f[0], f[1], hp, lp); H.u.x = hp; L.u.x = lp;
            cvt_pair(f[2], f[3], hp, lp); H.u.y = hp; L.u.y = lp;
            cvt_pair(f[4], f[5], hp, lp); H.u.z = hp; L.u.z = lp;
            cvt_pair(f[6], f[7], hp, lp); H.u.w = hp; L.u.w = lp;
            const int slot = chl * 4 + s;
            const int byte = n * 128 + ((slot * 16) ^ ((n & 7) * 16));
            *(uint4*)(zhi_ + byte) = H.u;
            *(uint4*)(zlo_ + byte) = L.u;
        }
    }
    __syncthreads();

    // ---- main loop: 16 n-tiles, NO barriers ----
    for (int nt = 0; nt < 16; ++nt) {
        const int nb = nt * 16 + (lane & 15);
        const int sw = (nb & 7) * 16;
        short8 zfh[2], zfl[2];
#pragma unroll
        for (int ks = 0; ks < 2; ++ks) {
            const int slot = ks * 4 + (lane >> 4);
            const int byte = nb * 128 + ((slot * 16) ^ sw);
            zfh[ks] = *(const short8*)(zhi_ + byte);
            zfl[ks] = *(const short8*)(zlo_ + byte);
        }
        const float finf = __uint_as_float(0x7F800000u);
        float m1 = finf, m2 = finf;
#pragma unroll
        for (int kt = 0; kt < 8; ++kt) {
            f32x4 acc = {0.f, 0.f, 0.f, 0.f};
            acc = __builtin_amdgcn_mfma_f32_16x16x32_bf16(afl[kt][0], zfh[0], acc, 0, 0, 0);
            acc = __builtin_amdgcn_mfma_f32_16x16x32_bf16(afh[kt][0], zfl[0], acc, 0, 0, 0);
            acc = __builtin_amdgcn_mfma_f32_16x16x32_bf16(afh[kt][0], zfh[0], acc, 0, 0, 0);
            acc = __builtin_amdgcn_mfma_f32_16x16x32_bf16(afl[kt][1], zfh[1], acc, 0, 0, 0);
            acc = __builtin_amdgcn_mfma_f32_16x16x32_bf16(afh[kt][1], zfl[1], acc, 0, 0, 0);
            acc = __builtin_amdgcn_mfma_f32_16x16x32_bf16(afh[kt][1], zfh[1], acc, 0, 0, 0);
            const int kbase = Kw + kt * 16 + ((lane >> 4) << 2);
#pragma unroll
            for (int r = 0; r < 4; ++r) {
                float s = fmaf(-2.0f, acc[r], cnv[kt][r]);
                float key = __uint_as_float(
                    (__float_as_uint(s) & 0xFFFFFC00u) | (uint32_t)(kbase + r));
                m2 = fminf(m2, fmaxf(key, m1));
                m1 = fminf(m1, key);
            }
        }
        // merge the 4 k-slices (lanes n, n+16, n+32, n+48)
#pragma unroll
        for (int off = 16; off <= 32; off <<= 1) {
            float o1 = __shfl_xor(m1, off);
            float o2 = __shfl_xor(m2, off);
            m2 = fminf(fminf(m2, o2), fmaxf(m1, o1));
            m1 = fminf(m1, o1);
        }
        if ((lane >> 4) == 0) {
            float2 v; v.x = m1; v.y = m2;
            wred[(nt * 16 + lane) * 9 + wv] = v;
        }
    }
    __syncthreads();

    // ---- cross-wave combine, zis write, ambiguity flagging (tid<256) ----
    if (tid < 256) {
        const float finf = __uint_as_float(0x7F800000u);
        float c1 = finf, c2 = finf;
#pragma unroll
        for (int w = 0; w < 8; ++w) {
            float2 v = wred[tid * 9 + w];
            c2 = fminf(fminf(c2, v.y), fmaxf(c1, v.x));
            c1 = fminf(c1, v.x);
        }
        const uint32_t u1 = __float_as_uint(c1);
        const int idx = (int)(u1 & 1023u);
        sfin[tid] = idx;
        out[n0g + tid] = (float)idx;
        const float v1 = __uint_as_float(u1 & 0xFFFFFC00u);
        const float v2 = __uint_as_float(__float_as_uint(c2) & 0xFFFFFC00u);
        if (v2 - v1 < DELTA) {
            int p = atomicAdd(ambcnt, 1);
            amblist[p] = tid;
        }
    }
    __syncthreads();

    // ---- exact rescreen, wave-parallel (r2-validated numerics) ----
    const int namb = *ambcnt;
    for (int i = wv; i < namb; i += 8) {
        const int n = amblist[i];
        // lane = channel; strided read of exact f32 z
        float zc = in[(((size_t)(b * CDIM + lane)) << 12) + hw0 + n];
        // bit-exact numpy pairwise znorm via shfl (r[j] sequential, tree combine)
        float sq = zc * zc;
        float accp = sq;
#pragma unroll
        for (int i2 = 1; i2 < 8; ++i2)
            accp = accp + __shfl(sq, i2 * 8 + (lane & 7));
        float t1 = accp + __shfl_xor(accp, 1);
        float t2 = t1 + __shfl_xor(t1, 2);
        float t3 = t2 + __shfl_xor(t2, 4);
        const float zn = __shfl(t3, 0);
        // broadcast z through LDS (wave-local), hoist to registers
        zsc[wv * 64 + lane] = zc;
        float zv[64];
#pragma unroll
        for (int q = 0; q < 16; ++q) {
            float4 v = *(const float4*)(&zsc[wv * 64 + q * 4]);
            zv[q * 4 + 0] = v.x; zv[q * 4 + 1] = v.y;
            zv[q * 4 + 2] = v.z; zv[q * 4 + 3] = v.w;
        }
        unsigned long long bestk = ~0ull;
#pragma unroll
        for (int j = 0; j < 16; ++j) {
            const int k = j * 64 + lane;
            const float4* e = (const float4*)(cb + (size_t)k * CDIM);
            float a0 = 0.f, a1 = 0.f, a2 = 0.f, a3 = 0.f;
#pragma unroll
            for (int i2 = 0; i2 < 4; ++i2) {
                float4 v0 = e[i2 * 4 + 0];
                float4 v1 = e[i2 * 4 + 1];
                float4 v2 = e[i2 * 4 + 2];
                float4 v3 = e[i2 * 4 + 3];
                RFMA4(a0, i2 * 16 + 0,  v0)
                RFMA4(a1, i2 * 16 + 4,  v1)
                RFMA4(a2, i2 * 16 + 8,  v2)
                RFMA4(a3, i2 * 16 + 12, v3)
            }
            float dot = (a0 + a1) + (a2 + a3);
            float t = zn + cnorm[k];   // fl(znorm + cnorm)
            float u = 2.0f * dot;      // fl(2*dot)
            float d = t - u;           // fl(t - u)
            unsigned long long key =
                ((unsigned long long)__float_as_uint(d) << 10) | (unsigned)k;
            bestk = key < bestk ? key : bestk;
        }
#pragma unroll
        for (int off = 32; off >= 1; off >>= 1) {
            unsigned long long o = shflxor64(bestk, off);
            bestk = o < bestk ? o : bestk;
        }
        if (lane == 0) {
            const int idx = (int)(bestk & 1023u);
            sfin[n] = idx;
            out[n0g + n] = (float)idx;
        }
    }
    __syncthreads();

    // ---- zqs epilogue: gather -> LDS transpose tile -> coalesced BCHW ----
    // two half-blocks work on two tiles in parallel; 2 rounds cover 4x64 pos
    float (*tileA)[65] = (float (*)[65])(smem + OFF_ZHI);
    float (*tileB)[65] = (float (*)[65])(smem + OFF_ZLO);
    const int half = tid >> 8;          // 0/1
    const int t    = tid & 255;
    float (*tile)[65] = half ? tileB : tileA;
    const float4* cb4 = (const float4*)cb;
    float* zqb = out + NPOS + (((size_t)b * CDIM) << 12) + hw0;
    for (int h = 0; h < 2; ++h) {
        const int tile_idx = half * 2 + h;
        {
            const int p = t >> 2, q = t & 3;
            const int idx = sfin[tile_idx * 64 + p];
            const float4* row = cb4 + (size_t)idx * (CDIM / 4) + q * 4;
#pragma unroll
            for (int i = 0; i < 4; ++i) {
                float4 v = row[i];
                const int c = q * 16 + i * 4;
                tile[p][c + 0] = v.x; tile[p][c + 1] = v.y;
                tile[p][c + 2] = v.z; tile[p][c + 3] = v.w;
            }
        }
        __syncthreads();
        {
            const int wv2 = t >> 6, lane2 = t & 63;
#pragma unroll
            for (int i = 0; i < 16; ++i) {
                const int c = i * 4 + wv2;
                zqb[((size_t)c << 12) + tile_idx * 64 + lane2] = tile[lane2][c];
            }
        }
        __syncthreads();
    }
}

extern "C" void kernel_launch(void* const* d_in, const int* in_sizes, int n_in,
                              void* d_out, int out_size, void* d_ws, size_t ws_size,
                              hipStream_t stream) {
    const float* in = (const float*)d_in[0];   // 16*64*64*64
    const float* cb = (const float*)d_in[1];   // 1024*64
    float* out   = (float*)d_out;              // 65536 + 4194304
    float* cnorm = (float*)d_ws;               // 1024 floats scratch

    vq_cnorm_kernel<<<NUM_K / 256, 256, 0, stream>>>(cb, cnorm);
    vq_main_kernel<<<NPOS / NPB, 512, 0, stream>>>(in, cb, cnorm, out);
}